// Round 5
// baseline (10362.712 us; speedup 1.0000x reference)
//
#include <hip/hip_runtime.h>

#define BATCH 65536
#define RT 32              // rows per block
#define NBLK (BATCH/RT)    // 2048
#define NTHR 512           // 8 waves: row-group = w>>2 (16 rows), col-quarter = w&3
#define HS 264             // bf16 elems per LDS row (256 + 8 pad; 528B = 16*33, 16B-aligned)

typedef __bf16 v8bf __attribute__((ext_vector_type(8)));
typedef float  v4f  __attribute__((ext_vector_type(4)));
#define MFMA __builtin_amdgcn_mfma_f32_16x16x32_bf16

// ws layout, bf16-element offsets
#define WHH_ELE 0          // 8kc x 4cq x 16nt x 64lane x 8j   (512KB)
#define WZ_ELE  262144     // same shape, W_ih[:, :256]        (512KB)
#define EXT_ELE 524288     // 4cq x 16nt x 64lane x 8j : one-hot table (64KB)
#define WT_ELE  557056     // 8kc x 64lane x 8j : W_t padded N=16 (8KB)
#define WM_ELE  561152     // 8kc x 64lane x 8j : W_m padded N=16 (8KB)
#define WS_ELE_TOTAL 565248

// d_out layout (float offsets): log_p | t_actions | m_actions | t_ent | m_ent
#define OUT_LP 0
#define OUT_TA 65536
#define OUT_MA 589824
#define OUT_TENT 1114112
#define OUT_MENT 1114113

__device__ __forceinline__ float sigf(float x){ return 1.0f/(1.0f+__expf(-x)); }
__device__ __forceinline__ float tanhf_(float x){
  x = fminf(fmaxf(x, -15.0f), 15.0f);
  float e = __expf(2.0f*x);
  return (e-1.0f)/(e+1.0f);
}
__device__ __forceinline__ unsigned short f32_to_bf16(float x){
  unsigned u = __float_as_uint(x);
  unsigned r = (u + 0x7fffu + ((u>>16)&1u)) >> 16;   // RNE
  return (unsigned short)r;
}

// gate-column permutation: col-quarter cq, ntile nt, col -> original gate row g
// g = (nt>>2)*256 + cq*64 + (nt&3)*16 + col
__global__ void precompute_kernel(const float* __restrict__ W_ih, const float* __restrict__ W_hh,
                                  const float* __restrict__ b_ih, const float* __restrict__ b_hh,
                                  const float* __restrict__ action_emb, const float* __restrict__ branch_emb,
                                  const float* __restrict__ actionid_emb,
                                  const float* __restrict__ W_t, const float* __restrict__ W_m,
                                  unsigned short* __restrict__ wsp, float* __restrict__ d_out) {
  int tid = blockIdx.x*256 + threadIdx.x;
  if (tid == 0) { d_out[OUT_TENT] = 0.f; d_out[OUT_MENT] = 0.f; }
  if (tid >= WS_ELE_TOTAL) return;
  float val = 0.f;
  if (tid < 524288) {                        // WHH / WZ packs
    int i = (tid < 262144) ? tid : tid - 262144;
    int j = i & 7, lane = (i>>3)&63, nt = (i>>9)&15, cq = (i>>13)&3, kc = (i>>15)&7;
    int k = kc*32 + (lane>>4)*8 + j;
    int g = (nt>>2)*256 + cq*64 + (nt&3)*16 + (lane&15);
    val = (tid < 262144) ? W_hh[g*256 + k] : W_ih[g*448 + k];
  } else if (tid < 557056) {                 // EXT: one-hot table, K=32
    int i = tid - 524288;
    int j = i & 7, lane = (i>>3)&63, nt = (i>>9)&15, cq = (i>>13)&3;
    int p = (lane>>4)*8 + j;                 // K index = table row
    int g = (nt>>2)*256 + cq*64 + (nt&3)*16 + (lane&15);
    if (p < 16) {                            // AE[p][g]
      float s = 0.f;
      for (int e=0;e<64;++e) s += action_emb[p*64+e]*W_ih[g*448+384+e];
      val = s;
    } else if (p < 20) {                     // bias + bid + aid
      int q = p-16, br = q>>1, aid = q&1;
      float s = b_ih[g] + b_hh[g];
      for (int e=0;e<64;++e)
        s += branch_emb[br*64+e]*W_ih[g*448+256+e] + actionid_emb[aid*64+e]*W_ih[g*448+320+e];
      val = s;
    }
  } else {                                   // WT / WM packs (N padded to 16)
    int base = (tid < 561152) ? 557056 : 561152;
    int i = tid - base;
    int j = i & 7, lane = (i>>3)&63, kc = (i>>9)&7;
    int k = kc*32 + (lane>>4)*8 + j;
    int a = lane & 15;
    if (tid < 561152) val = (a < 4)  ? W_t[a*256 + k] : 0.f;
    else              val = (a < 11) ? W_m[a*256 + k] : 0.f;
  }
  wsp[tid] = f32_to_bf16(val);
}

// acc[nt] += A(16 rows from hrow) * Bpack over K=256; hrow pre-offset to (rg16+col)*HS + quad*8
__device__ __forceinline__ void run_gemm(v4f acc[16], const v8bf* __restrict__ Bw,
                                         const unsigned short* hrow) {
  #pragma unroll
  for (int kc = 0; kc < 8; ++kc) {
    v8bf A = *(const v8bf*)&hrow[kc*32];
    #pragma unroll
    for (int nt = 0; nt < 16; ++nt)
      acc[nt] = MFMA(A, Bw[kc*4096 + nt*64], acc[nt], 0,0,0);
  }
}

__global__ __launch_bounds__(NTHR, 2) void decoder_main(
    const float* __restrict__ z1, const float* __restrict__ z2,
    const int* __restrict__ t_act, const int* __restrict__ m_act,
    const float* __restrict__ b_t, const float* __restrict__ b_m,
    const unsigned short* __restrict__ wsp, float* __restrict__ d_out) {
  __shared__ __align__(16) unsigned short h_lds[RT*HS];    // 16.9KB, [row][k] bf16
  __shared__ __align__(16) unsigned short z_lds[RT*HS];    // 16.9KB
  __shared__ __align__(16) unsigned short ext_l[32768];    // 64KB one-hot table
  __shared__ __align__(16) unsigned short wt_l[4096];      // 8KB
  __shared__ __align__(16) unsigned short wm_l[4096];      // 8KB
  __shared__ float tl_lds[RT*4];
  __shared__ float ml_lds[RT*12];
  __shared__ int prev_lds[RT], ta_lds[RT], ma_lds[RT];
  __shared__ float ent_arr[2*RT];

  const int t = threadIdx.x, w = t>>6, l = t&63, col = l&15, quad = l>>4;
  const int cq = w&3, rg16 = (w>>2)*16;     // col-quarter, row-group base
  const int r0 = blockIdx.x * RT;
  const v8bf* Bhh = ((const v8bf*)(wsp + WHH_ELE)) + cq*1024 + l;
  const v8bf* Bz  = ((const v8bf*)(wsp + WZ_ELE))  + cq*1024 + l;
  const v8bf* Ew  = ((const v8bf*)ext_l) + cq*1024 + l;
  const v8bf* Wtp = ((const v8bf*)wt_l) + l;
  const v8bf* Wmp = ((const v8bf*)wm_l) + l;

  // stage one-hot/logit weight tables into LDS (read 16x per block)
  // BUGFIX r4->r5: with NTHR=512 the old `else if (t<1024)` branch for wm_l
  // was dead code -> wm_l uninitialized -> garbage m-logits. Stage both here.
  for (int i = t; i < 4096; i += NTHR) ((uint4*)ext_l)[i] = ((const uint4*)(wsp + EXT_ELE))[i];
  if (t < 512) {
    ((uint4*)wt_l)[t] = ((const uint4*)(wsp + WT_ELE))[t];
    ((uint4*)wm_l)[t] = ((const uint4*)(wsp + WM_ELE))[t];
  }
  for (int i = t; i < RT*HS; i += NTHR) h_lds[i] = 0;
  if (t < RT) prev_lds[t] = 15;             // LEN_ACT-1

  float c_st[4][4];
  #pragma unroll
  for (int n=0;n<4;++n)
    #pragma unroll
    for (int rg=0;rg<4;++rg) c_st[n][rg]=0.f;
  float lp = 0.f, entT = 0.f, entM = 0.f;
  int mask = 0xF;

  for (int br = 0; br < 2; ++br) {
    const float* z = br ? z2 : z1;
    // stage z -> LDS bf16, A-layout [row][k]: 512 thr x 2 iters x 8 floats
    #pragma unroll
    for (int it = 0; it < 2; ++it) {
      int r = (t>>5) + it*16, c0 = (t&31)*8;
      const float4 f0 = *(const float4*)&z[(r0+r)*256 + c0];
      const float4 f1 = *(const float4*)&z[(r0+r)*256 + c0 + 4];
      uint4 pk;
      pk.x = (unsigned)f32_to_bf16(f0.x) | ((unsigned)f32_to_bf16(f0.y)<<16);
      pk.y = (unsigned)f32_to_bf16(f0.z) | ((unsigned)f32_to_bf16(f0.w)<<16);
      pk.z = (unsigned)f32_to_bf16(f1.x) | ((unsigned)f32_to_bf16(f1.y)<<16);
      pk.w = (unsigned)f32_to_bf16(f1.z) | ((unsigned)f32_to_bf16(f1.w)<<16);
      *(uint4*)&z_lds[r*HS + c0] = pk;
    }
    mask = 0xF;
    __syncthreads();

    // base = z @ Wz^T (fp32, registers)
    v4f base[16];
    #pragma unroll
    for (int nt=0;nt<16;++nt) base[nt] = (v4f){0.f,0.f,0.f,0.f};
    run_gemm(base, Bz, &z_lds[(rg16+col)*HS + quad*8]);

    for (int s = 0; s < 4; ++s) {
      if (t < RT) {
        ta_lds[t] = t_act[(r0+t)*8 + br*4 + s];
        ma_lds[t] = m_act[(r0+t)*8 + br*4 + s];
      }
      __syncthreads();                                   // (1) ta/ma/prev visible

      // ---- LSTM 1 : gates = base + h@Whh^T + onehot(prev, bias[br][0]) ----
      v4f acc[16];
      #pragma unroll
      for (int nt=0;nt<16;++nt) acc[nt] = base[nt];
      run_gemm(acc, Bhh, &h_lds[(rg16+col)*HS + quad*8]);
      {
        int p0 = prev_lds[rg16 + col], cidx = 16 + 2*br + 0;
        v8bf oh;
        #pragma unroll
        for (int j=0;j<8;++j) { int k = quad*8+j; oh[j] = (k==p0 || k==cidx) ? (__bf16)1.0f : (__bf16)0.0f; }
        #pragma unroll
        for (int nt=0;nt<16;++nt) acc[nt] = MFMA(oh, Ew[nt*64], acc[nt], 0,0,0);
      }
      float hv[4][4];
      #pragma unroll
      for (int n=0;n<4;++n)
        #pragma unroll
        for (int rg=0;rg<4;++rg) {
          float gi = sigf(acc[n][rg]);
          float gf = sigf(acc[n+4][rg]);
          float gg = tanhf_(acc[n+8][rg]);
          float go = sigf(acc[n+12][rg]);
          float cn = gf*c_st[n][rg] + gi*gg;
          c_st[n][rg] = cn;
          hv[n][rg] = go*tanhf_(cn);
        }
      __syncthreads();                                   // (2) all h reads done
      #pragma unroll
      for (int n=0;n<4;++n)
        #pragma unroll
        for (int rg=0;rg<4;++rg)
          h_lds[(rg16 + quad*4 + rg)*HS + cq*64 + n*16 + col] = f32_to_bf16(hv[n][rg]);
      __syncthreads();                                   // (3) new h visible

      // ---- t-logits via MFMA (col-quarter-0 waves; N padded 16, 4 valid) ----
      if (cq == 0) {
        v4f lacc = (v4f){0.f,0.f,0.f,0.f};
        #pragma unroll
        for (int kc=0;kc<8;++kc) {
          v8bf A = *(const v8bf*)&h_lds[(rg16+col)*HS + kc*32 + quad*8];
          lacc = MFMA(A, Wtp[kc*64], lacc, 0,0,0);
        }
        if (col < 4) {
          #pragma unroll
          for (int rg=0;rg<4;++rg) tl_lds[(rg16 + quad*4 + rg)*4 + col] = lacc[rg];
        }
      }
      __syncthreads();                                   // (4) logits visible
      if (t < RT) {
        int ta = ta_lds[t];
        float tl[4];
        #pragma unroll
        for (int a=0;a<4;++a) {
          float raw = tl_lds[t*4+a] + b_t[a];
          tl[a] = ((mask>>a)&1) ? raw : -1e9f;
        }
        float mx = fmaxf(fmaxf(tl[0],tl[1]),fmaxf(tl[2],tl[3]));
        float se = 0.f;
        #pragma unroll
        for (int a=0;a<4;++a) se += __expf(tl[a]-mx);
        float lse = mx + __logf(se);
        lp += tl[ta] - lse;
        float e = 0.f;
        #pragma unroll
        for (int a=0;a<4;++a) if ((mask>>a)&1) { float l2 = tl[a]-lse; e -= __expf(l2)*l2; }
        entT += e;
        mask &= ~(1<<ta);
      }

      // ---- LSTM 2 : gates = base + h@Whh^T + onehot(ta, bias[br][1]) ----
      #pragma unroll
      for (int nt=0;nt<16;++nt) acc[nt] = base[nt];
      run_gemm(acc, Bhh, &h_lds[(rg16+col)*HS + quad*8]);
      {
        int p0 = ta_lds[rg16 + col], cidx = 16 + 2*br + 1;
        v8bf oh;
        #pragma unroll
        for (int j=0;j<8;++j) { int k = quad*8+j; oh[j] = (k==p0 || k==cidx) ? (__bf16)1.0f : (__bf16)0.0f; }
        #pragma unroll
        for (int nt=0;nt<16;++nt) acc[nt] = MFMA(oh, Ew[nt*64], acc[nt], 0,0,0);
      }
      #pragma unroll
      for (int n=0;n<4;++n)
        #pragma unroll
        for (int rg=0;rg<4;++rg) {
          float gi = sigf(acc[n][rg]);
          float gf = sigf(acc[n+4][rg]);
          float gg = tanhf_(acc[n+8][rg]);
          float go = sigf(acc[n+12][rg]);
          float cn = gf*c_st[n][rg] + gi*gg;
          c_st[n][rg] = cn;
          hv[n][rg] = go*tanhf_(cn);
        }
      __syncthreads();                                   // (5)
      #pragma unroll
      for (int n=0;n<4;++n)
        #pragma unroll
        for (int rg=0;rg<4;++rg)
          h_lds[(rg16 + quad*4 + rg)*HS + cq*64 + n*16 + col] = f32_to_bf16(hv[n][rg]);
      __syncthreads();                                   // (6)

      // ---- m-logits via MFMA (col-quarter-0 waves; 11 valid) ----
      if (cq == 0) {
        v4f lacc = (v4f){0.f,0.f,0.f,0.f};
        #pragma unroll
        for (int kc=0;kc<8;++kc) {
          v8bf A = *(const v8bf*)&h_lds[(rg16+col)*HS + kc*32 + quad*8];
          lacc = MFMA(A, Wmp[kc*64], lacc, 0,0,0);
        }
        if (col < 11) {
          #pragma unroll
          for (int rg=0;rg<4;++rg) ml_lds[(rg16 + quad*4 + rg)*12 + col] = lacc[rg];
        }
      }
      __syncthreads();                                   // (7)
      if (t < RT) {
        int ma = ma_lds[t];
        float mlv[11];
        #pragma unroll
        for (int a=0;a<11;++a) mlv[a] = ml_lds[t*12+a] + b_m[a];
        float mx = mlv[0];
        #pragma unroll
        for (int a=1;a<11;++a) mx = fmaxf(mx, mlv[a]);
        float se = 0.f;
        #pragma unroll
        for (int a=0;a<11;++a) se += __expf(mlv[a]-mx);
        float lse = mx + __logf(se);
        lp += mlv[ma] - lse;
        float e = 0.f;
        #pragma unroll
        for (int a=0;a<11;++a) { float l2 = mlv[a]-lse; e -= __expf(l2)*l2; }
        entM += e;
        prev_lds[t] = ma;                                // carry (synced by next (1))
      }
    }
  }

  // ---- outputs ----
  if (t < RT) {
    d_out[OUT_LP + r0 + t] = lp;
    ent_arr[t] = entT;
    ent_arr[RT + t] = entM;
  }
  __syncthreads();
  if (t == 0) {
    float sT=0.f, sM=0.f;
    for (int i=0;i<RT;++i){ sT+=ent_arr[i]; sM+=ent_arr[RT+i]; }
    const float inv = 1.0f/524288.0f;                    // 1/(B*2S), exact 2^-19
    atomicAdd(d_out + OUT_TENT, sT*inv);
    atomicAdd(d_out + OUT_MENT, sM*inv);
  }
  if (t < 256) {                                         // passthrough, int -> float
    d_out[OUT_TA + r0*8 + t] = (float)t_act[r0*8 + t];
    d_out[OUT_MA + r0*8 + t] = (float)m_act[r0*8 + t];
  }
}

extern "C" void kernel_launch(void* const* d_in, const int* in_sizes, int n_in,
                              void* d_out, int out_size, void* d_ws, size_t ws_size,
                              hipStream_t stream) {
  const float* z1           = (const float*)d_in[0];
  const float* z2           = (const float*)d_in[1];
  const int*   t_act        = (const int*)d_in[2];
  const int*   m_act        = (const int*)d_in[3];
  const float* action_emb   = (const float*)d_in[4];
  const float* branch_emb   = (const float*)d_in[5];
  const float* actionid_emb = (const float*)d_in[6];
  const float* W_ih         = (const float*)d_in[7];
  const float* W_hh         = (const float*)d_in[8];
  const float* b_ih         = (const float*)d_in[9];
  const float* b_hh         = (const float*)d_in[10];
  const float* W_t          = (const float*)d_in[11];
  const float* b_t          = (const float*)d_in[12];
  const float* W_m          = (const float*)d_in[13];
  const float* b_m          = (const float*)d_in[14];
  float* out = (float*)d_out;
  unsigned short* wsp = (unsigned short*)d_ws;   // 565248 bf16 = 1.13MB

  precompute_kernel<<<(WS_ELE_TOTAL+255)/256, 256, 0, stream>>>(
      W_ih, W_hh, b_ih, b_hh, action_emb, branch_emb, actionid_emb, W_t, W_m, wsp, out);
  decoder_main<<<NBLK, NTHR, 0, stream>>>(z1, z2, t_act, m_act, b_t, b_m, wsp, out);
}

// Round 6
// 2967.562 us; speedup vs baseline: 3.4920x; 3.4920x over previous
//
#include <hip/hip_runtime.h>

#define BATCH 65536
#define RT 64              // rows per block
#define NBLK (BATCH/RT)    // 1024
#define NTHR 512           // 8 waves; wave w owns all 64 rows x (units w*32..w*32+31) x 4 gates
#define HS 264             // bf16 elems per LDS h row (256 + 8 pad)

typedef __bf16 v8bf __attribute__((ext_vector_type(8)));
typedef float  v4f  __attribute__((ext_vector_type(4)));
#define MFMA __builtin_amdgcn_mfma_f32_16x16x32_bf16

// ws layout, bf16-element offsets
// B packs: [kc 8][w 8][nt 8][lane 64][j 8]; nt = gate*2 + ub; col g = gate*256 + w*32 + ub*16 + (lane&15)
#define WHH_ELE 0
#define WZ_ELE  262144
#define EXT_ELE 524288     // [w 8][nt 8][lane 64][j 8], K=32 one-hot table (p=(lane>>4)*8+j)
#define WT_ELE  557056     // [kc 8][lane 64][j 8], N=16 (4 valid)
#define WM_ELE  561152     // [kc 8][lane 64][j 8], N=16 (11 valid)
#define WS_ELE_TOTAL 565248

// d_out layout (float offsets): log_p | t_actions | m_actions | t_ent | m_ent
#define OUT_LP 0
#define OUT_TA 65536
#define OUT_MA 589824
#define OUT_TENT 1114112
#define OUT_MENT 1114113

__device__ __forceinline__ float sigf(float x){ return 1.0f/(1.0f+__expf(-x)); }
__device__ __forceinline__ float tanhf_(float x){
  x = fminf(fmaxf(x, -15.0f), 15.0f);
  float e = __expf(2.0f*x);
  return (e-1.0f)/(e+1.0f);
}
__device__ __forceinline__ unsigned short f32_to_bf16(float x){
  unsigned u = __float_as_uint(x);
  unsigned r = (u + 0x7fffu + ((u>>16)&1u)) >> 16;   // RNE
  return (unsigned short)r;
}

__global__ void precompute_kernel(const float* __restrict__ W_ih, const float* __restrict__ W_hh,
                                  const float* __restrict__ b_ih, const float* __restrict__ b_hh,
                                  const float* __restrict__ action_emb, const float* __restrict__ branch_emb,
                                  const float* __restrict__ actionid_emb,
                                  const float* __restrict__ W_t, const float* __restrict__ W_m,
                                  unsigned short* __restrict__ wsp, float* __restrict__ d_out) {
  int tid = blockIdx.x*256 + threadIdx.x;
  if (tid == 0) { d_out[OUT_TENT] = 0.f; d_out[OUT_MENT] = 0.f; }
  if (tid >= WS_ELE_TOTAL) return;
  float val = 0.f;
  if (tid < 524288) {                        // WHH / WZ packs
    int i = (tid < 262144) ? tid : tid - 262144;
    int j = i & 7, lane = (i>>3)&63, nt = (i>>9)&7, w = (i>>12)&7, kc = (i>>15)&7;
    int k = kc*32 + (lane>>4)*8 + j;
    int g = (nt>>1)*256 + w*32 + (nt&1)*16 + (lane&15);
    val = (tid < 262144) ? W_hh[g*256 + k] : W_ih[g*448 + k];
  } else if (tid < 557056) {                 // EXT one-hot table, K=32
    int i = tid - 524288;
    int j = i & 7, lane = (i>>3)&63, nt = (i>>9)&7, w = (i>>12)&7;
    int p = (lane>>4)*8 + j;
    int g = (nt>>1)*256 + w*32 + (nt&1)*16 + (lane&15);
    if (p < 16) {                            // action_emb[p] @ W_ih[:,384:448].T
      float s = 0.f;
      for (int e=0;e<64;++e) s += action_emb[p*64+e]*W_ih[g*448+384+e];
      val = s;
    } else if (p < 20) {                     // bias + branch + actionid, cidx = 16+2*br+aid
      int q = p-16, br = q>>1, aid = q&1;
      float s = b_ih[g] + b_hh[g];
      for (int e=0;e<64;++e)
        s += branch_emb[br*64+e]*W_ih[g*448+256+e] + actionid_emb[aid*64+e]*W_ih[g*448+320+e];
      val = s;
    }
  } else {                                   // WT / WM packs
    int base = (tid < 561152) ? 557056 : 561152;
    int i = tid - base;
    int j = i & 7, lane = (i>>3)&63, kc = (i>>9)&7;
    int k = kc*32 + (lane>>4)*8 + j;
    int a = lane & 15;
    if (tid < 561152) val = (a < 4)  ? W_t[a*256 + k] : 0.f;
    else              val = (a < 11) ? W_m[a*256 + k] : 0.f;
  }
  wsp[tid] = f32_to_bf16(val);
}

// acc[mt][nt] += A(rows mt*16..+15 from lds) * B over K=256
__device__ __forceinline__ void run_gemm(v4f acc[4][8], const v8bf* __restrict__ Bw,
                                         const unsigned short* __restrict__ lds, int col, int quad) {
  #pragma unroll 2
  for (int kc = 0; kc < 8; ++kc) {
    v8bf A[4];
    #pragma unroll
    for (int mt=0;mt<4;++mt)
      A[mt] = *(const v8bf*)&lds[(mt*16+col)*HS + kc*32 + quad*8];
    #pragma unroll
    for (int nt=0;nt<8;++nt) {
      v8bf B = Bw[kc*4096 + nt*64];
      #pragma unroll
      for (int mt=0;mt<4;++mt)
        acc[mt][nt] = MFMA(A[mt], B, acc[mt][nt], 0,0,0);
    }
  }
}

// one-hot K=32 chunk: per row adds EXT[idx_row] + EXT[cidx]
__device__ __forceinline__ void run_ext(v4f acc[4][8], const v8bf* __restrict__ Ew,
                                        const int* __restrict__ idx, int cidx, int col, int quad) {
  #pragma unroll
  for (int mt=0;mt<4;++mt) {
    int p0 = idx[mt*16 + col];
    v8bf oh;
    #pragma unroll
    for (int j=0;j<8;++j) { int k = quad*8+j; oh[j] = (k==p0 || k==cidx) ? (__bf16)1.0f : (__bf16)0.0f; }
    #pragma unroll
    for (int nt=0;nt<8;++nt)
      acc[mt][nt] = MFMA(oh, Ew[nt*64], acc[mt][nt], 0,0,0);
  }
}

__global__ __launch_bounds__(NTHR, 1) void decoder_main(
    const float* __restrict__ z1, const float* __restrict__ z2,
    const int* __restrict__ t_act, const int* __restrict__ m_act,
    const float* __restrict__ b_t, const float* __restrict__ b_m,
    const unsigned short* __restrict__ wsp, float* __restrict__ d_out) {
  __shared__ __align__(16) unsigned short hA[RT*HS];    // 33.8KB, [row][k] bf16
  __shared__ __align__(16) unsigned short hB[RT*HS];    // 33.8KB (double buffer)
  __shared__ __align__(16) unsigned short z_lds[RT*HS]; // 33.8KB
  __shared__ float tl_lds[RT*4];
  __shared__ float ml_lds[RT*12];
  __shared__ int ta_l[4*RT], ma_l[4*RT], pa_l[4*RT], carry_l[RT];

  const int t = threadIdx.x, wv = t>>6, l = t&63, col = l&15, quad = l>>4;
  const int r0 = blockIdx.x * RT;
  const v8bf* Bhh = ((const v8bf*)(wsp + WHH_ELE)) + wv*512 + l;
  const v8bf* Bz  = ((const v8bf*)(wsp + WZ_ELE))  + wv*512 + l;
  const v8bf* Ew  = ((const v8bf*)(wsp + EXT_ELE)) + wv*512 + l;
  const v8bf* Wtp = ((const v8bf*)(wsp + WT_ELE))  + l;
  const v8bf* Wmp = ((const v8bf*)(wsp + WM_ELE))  + l;

  for (int i = t; i < RT*HS; i += NTHR) hA[i] = 0;

  float c_st[4][2][4];
  #pragma unroll
  for (int mt=0;mt<4;++mt)
    #pragma unroll
    for (int ub=0;ub<2;++ub)
      #pragma unroll
      for (int rg=0;rg<4;++rg) c_st[mt][ub][rg]=0.f;
  float lp = 0.f, entT = 0.f, entM = 0.f;
  int mask = 0xF;

  v4f acc[4][8];
  unsigned bpk[4][8][2];      // base = z@Wz^T packed as bf16 pairs (per branch)

  for (int br = 0; br < 2; ++br) {
    const float* z = br ? z2 : z1;
    // ---- branch head: stage z (bf16 A-layout), ta, ma ----
    #pragma unroll
    for (int it = 0; it < 4; ++it) {
      int idx = t + it*NTHR;            // 0..2047 ; 64 rows x 32 chunks of 8 floats
      int r = idx>>5, c8 = idx&31;
      const float4 f0 = *(const float4*)&z[(r0+r)*256 + c8*8];
      const float4 f1 = *(const float4*)&z[(r0+r)*256 + c8*8 + 4];
      uint4 pk;
      pk.x = (unsigned)f32_to_bf16(f0.x) | ((unsigned)f32_to_bf16(f0.y)<<16);
      pk.y = (unsigned)f32_to_bf16(f0.z) | ((unsigned)f32_to_bf16(f0.w)<<16);
      pk.z = (unsigned)f32_to_bf16(f1.x) | ((unsigned)f32_to_bf16(f1.y)<<16);
      pk.w = (unsigned)f32_to_bf16(f1.z) | ((unsigned)f32_to_bf16(f1.w)<<16);
      *(uint4*)&z_lds[r*HS + c8*8] = pk;
    }
    if (t < 256)      { int e = t;     ta_l[(e&3)*RT + (e>>2)] = t_act[(r0+(e>>2))*8 + br*4 + (e&3)]; }
    else              { int e = t-256; ma_l[(e&3)*RT + (e>>2)] = m_act[(r0+(e>>2))*8 + br*4 + (e&3)]; }
    mask = 0xF;
    __syncthreads();
    if (t < RT) {                       // prev chain: all inputs (prev = ma of previous step)
      pa_l[t]        = (br==0) ? 15 : carry_l[t];
      pa_l[RT + t]   = ma_l[t];
      pa_l[2*RT + t] = ma_l[RT + t];
      pa_l[3*RT + t] = ma_l[2*RT + t];
      carry_l[t]     = ma_l[3*RT + t];
    }
    __syncthreads();

    // ---- base = z @ Wz^T, packed bf16 into registers ----
    #pragma unroll
    for (int mt=0;mt<4;++mt)
      #pragma unroll
      for (int nt=0;nt<8;++nt) acc[mt][nt] = (v4f){0.f,0.f,0.f,0.f};
    run_gemm(acc, Bz, z_lds, col, quad);
    #pragma unroll
    for (int mt=0;mt<4;++mt)
      #pragma unroll
      for (int nt=0;nt<8;++nt) {
        bpk[mt][nt][0] = (unsigned)f32_to_bf16(acc[mt][nt][0]) | ((unsigned)f32_to_bf16(acc[mt][nt][1])<<16);
        bpk[mt][nt][1] = (unsigned)f32_to_bf16(acc[mt][nt][2]) | ((unsigned)f32_to_bf16(acc[mt][nt][3])<<16);
      }

    for (int s = 0; s < 4; ++s) {
      // ==== P1: LSTM1 (read hA -> write hB) ====
      #pragma unroll
      for (int mt=0;mt<4;++mt)
        #pragma unroll
        for (int nt=0;nt<8;++nt) {
          unsigned p0 = bpk[mt][nt][0], p1 = bpk[mt][nt][1];
          acc[mt][nt] = (v4f){ __uint_as_float(p0<<16), __uint_as_float(p0 & 0xffff0000u),
                               __uint_as_float(p1<<16), __uint_as_float(p1 & 0xffff0000u) };
        }
      run_ext(acc, Ew, &pa_l[s*RT], 16 + 2*br + 0, col, quad);
      run_gemm(acc, Bhh, hA, col, quad);
      #pragma unroll
      for (int mt=0;mt<4;++mt)
        #pragma unroll
        for (int ub=0;ub<2;++ub)
          #pragma unroll
          for (int rg=0;rg<4;++rg) {
            float gi = sigf(acc[mt][0+ub][rg]);
            float gf = sigf(acc[mt][2+ub][rg]);
            float gg = tanhf_(acc[mt][4+ub][rg]);
            float go = sigf(acc[mt][6+ub][rg]);
            float cn = gf*c_st[mt][ub][rg] + gi*gg;
            c_st[mt][ub][rg] = cn;
            hB[(mt*16 + quad*4 + rg)*HS + wv*32 + ub*16 + col] = f32_to_bf16(go*tanhf_(cn));
          }
      __syncthreads();                                   // B1: hB visible

      // ==== P2: LSTM2 (read hB -> write hA) + t-logits (read hB) ====
      #pragma unroll
      for (int mt=0;mt<4;++mt)
        #pragma unroll
        for (int nt=0;nt<8;++nt) {
          unsigned p0 = bpk[mt][nt][0], p1 = bpk[mt][nt][1];
          acc[mt][nt] = (v4f){ __uint_as_float(p0<<16), __uint_as_float(p0 & 0xffff0000u),
                               __uint_as_float(p1<<16), __uint_as_float(p1 & 0xffff0000u) };
        }
      run_ext(acc, Ew, &ta_l[s*RT], 16 + 2*br + 1, col, quad);
      run_gemm(acc, Bhh, hB, col, quad);
      if (wv < 4) {                                      // t-logits: wave wv -> rows wv*16..
        v4f lacc = (v4f){0.f,0.f,0.f,0.f};
        #pragma unroll
        for (int kc=0;kc<8;++kc) {
          v8bf A = *(const v8bf*)&hB[(wv*16+col)*HS + kc*32 + quad*8];
          lacc = MFMA(A, Wtp[kc*64], lacc, 0,0,0);
        }
        if (col < 4) {
          #pragma unroll
          for (int rg=0;rg<4;++rg) tl_lds[(wv*16 + quad*4 + rg)*4 + col] = lacc[rg];
        }
      }
      #pragma unroll
      for (int mt=0;mt<4;++mt)
        #pragma unroll
        for (int ub=0;ub<2;++ub)
          #pragma unroll
          for (int rg=0;rg<4;++rg) {
            float gi = sigf(acc[mt][0+ub][rg]);
            float gf = sigf(acc[mt][2+ub][rg]);
            float gg = tanhf_(acc[mt][4+ub][rg]);
            float go = sigf(acc[mt][6+ub][rg]);
            float cn = gf*c_st[mt][ub][rg] + gi*gg;
            c_st[mt][ub][rg] = cn;
            hA[(mt*16 + quad*4 + rg)*HS + wv*32 + ub*16 + col] = f32_to_bf16(go*tanhf_(cn));
          }
      __syncthreads();                                   // B2: hA + tl visible

      // ==== P3: m-logits (waves 4-7, read hA) + softmax-t (wave 0) ====
      if (wv >= 4) {
        v4f lacc = (v4f){0.f,0.f,0.f,0.f};
        #pragma unroll
        for (int kc=0;kc<8;++kc) {
          v8bf A = *(const v8bf*)&hA[((wv-4)*16+col)*HS + kc*32 + quad*8];
          lacc = MFMA(A, Wmp[kc*64], lacc, 0,0,0);
        }
        if (col < 11) {
          #pragma unroll
          for (int rg=0;rg<4;++rg) ml_lds[((wv-4)*16 + quad*4 + rg)*12 + col] = lacc[rg];
        }
      }
      if (t < RT) {
        int ta = ta_l[s*RT + t];
        float tl[4];
        #pragma unroll
        for (int a=0;a<4;++a) {
          float raw = tl_lds[t*4+a] + b_t[a];
          tl[a] = ((mask>>a)&1) ? raw : -1e9f;
        }
        float mx = fmaxf(fmaxf(tl[0],tl[1]),fmaxf(tl[2],tl[3]));
        float se = 0.f;
        #pragma unroll
        for (int a=0;a<4;++a) se += __expf(tl[a]-mx);
        float lse = mx + __logf(se);
        lp += tl[ta] - lse;
        float e = 0.f;
        #pragma unroll
        for (int a=0;a<4;++a) if ((mask>>a)&1) { float l2 = tl[a]-lse; e -= __expf(l2)*l2; }
        entT += e;
        mask &= ~(1<<ta);
      }
      __syncthreads();                                   // B3: ml visible

      // ==== P4: softmax-m (wave 0) — overlaps next step's P1 for other waves ====
      if (t < RT) {
        int ma = ma_l[s*RT + t];
        float mlv[11];
        #pragma unroll
        for (int a=0;a<11;++a) mlv[a] = ml_lds[t*12+a] + b_m[a];
        float mx = mlv[0];
        #pragma unroll
        for (int a=1;a<11;++a) mx = fmaxf(mx, mlv[a]);
        float se = 0.f;
        #pragma unroll
        for (int a=0;a<11;++a) se += __expf(mlv[a]-mx);
        float lse = mx + __logf(se);
        lp += mlv[ma] - lse;
        float e = 0.f;
        #pragma unroll
        for (int a=0;a<11;++a) { float l2 = mlv[a]-lse; e -= __expf(l2)*l2; }
        entM += e;
      }
      // no barrier: ml_lds next written in P3(s+1), after B1/B2; tl next written in P2(s+1) after B1
    }
  }

  // ---- outputs ----
  if (t < RT) {
    d_out[OUT_LP + r0 + t] = lp;
    float sT = entT, sM = entM;
    #pragma unroll
    for (int off=32; off; off>>=1) { sT += __shfl_down(sT, off, 64); sM += __shfl_down(sM, off, 64); }
    if (t == 0) {
      const float inv = 1.0f/524288.0f;                  // 1/(B*2S), exact 2^-19
      atomicAdd(d_out + OUT_TENT, sT*inv);
      atomicAdd(d_out + OUT_MENT, sM*inv);
    }
  }
  // passthrough copies: RT*8 = 512 elements each, one per thread
  d_out[OUT_TA + r0*8 + t] = (float)t_act[r0*8 + t];
  d_out[OUT_MA + r0*8 + t] = (float)m_act[r0*8 + t];
}

extern "C" void kernel_launch(void* const* d_in, const int* in_sizes, int n_in,
                              void* d_out, int out_size, void* d_ws, size_t ws_size,
                              hipStream_t stream) {
  const float* z1           = (const float*)d_in[0];
  const float* z2           = (const float*)d_in[1];
  const int*   t_act        = (const int*)d_in[2];
  const int*   m_act        = (const int*)d_in[3];
  const float* action_emb   = (const float*)d_in[4];
  const float* branch_emb   = (const float*)d_in[5];
  const float* actionid_emb = (const float*)d_in[6];
  const float* W_ih         = (const float*)d_in[7];
  const float* W_hh         = (const float*)d_in[8];
  const float* b_ih         = (const float*)d_in[9];
  const float* b_hh         = (const float*)d_in[10];
  const float* W_t          = (const float*)d_in[11];
  const float* b_t          = (const float*)d_in[12];
  const float* W_m          = (const float*)d_in[13];
  const float* b_m          = (const float*)d_in[14];
  float* out = (float*)d_out;
  unsigned short* wsp = (unsigned short*)d_ws;   // 565248 bf16 = 1.13MB

  precompute_kernel<<<(WS_ELE_TOTAL+255)/256, 256, 0, stream>>>(
      W_ih, W_hh, b_ih, b_hh, action_emb, branch_emb, actionid_emb, W_t, W_m, wsp, out);
  decoder_main<<<NBLK, NTHR, 0, stream>>>(z1, z2, t_act, m_act, b_t, b_m, wsp, out);
}